// Round 4
// baseline (500.076 us; speedup 1.0000x reference)
//
#include <hip/hip_runtime.h>
#include <hip/hip_bf16.h>

#define B_ 2
#define S_ 2048
#define E_ 1024
#define H_ 16
#define D_ 64

typedef __bf16 bf16x8 __attribute__((ext_vector_type(8)));
typedef __bf16 bf16x4 __attribute__((ext_vector_type(4)));
typedef float f32x4 __attribute__((ext_vector_type(4)));

// ws layout in bf16 elements:
//   x_bf     : [4096, 1024]        offset 0         (4194304)
//   qkvw_bf  : [3072, 1024]        offset 4194304   (3145728)
//   projw_bf : [1024, 1024]        offset 7340032   (1048576)
//   qk_bf    : [2][B,H,S,D]        offset 8388608   (8388608)
//   vt_bf    : [B,H,D,S]           offset 16777216  (4194304)
//   attn_bf  : [4096, 1024]        offset 20971520  (4194304)
// total 25165824 elem = 48 MiB

__device__ __forceinline__ f32x4 mfma16(bf16x8 a, bf16x8 b, f32x4 c) {
    return __builtin_amdgcn_mfma_f32_16x16x32_bf16(a, b, c, 0, 0, 0);
}

__global__ __launch_bounds__(256) void convert_kernel(
        const float* __restrict__ x, const float* __restrict__ qkvw,
        const float* __restrict__ projw, __bf16* __restrict__ ws) {
    const long NX = 4194304, NW = 3145728;
    long i = (long)(blockIdx.x * 256 + threadIdx.x) * 4;
    const float* src; __bf16* dst; long off;
    if (i < NX)           { src = x;     dst = ws;           off = i; }
    else if (i < NX + NW) { src = qkvw;  dst = ws + NX;      off = i - NX; }
    else                  { src = projw; dst = ws + NX + NW; off = i - NX - NW; }
    float4 v = *(const float4*)(src + off);
    bf16x4 o = { (__bf16)v.x, (__bf16)v.y, (__bf16)v.z, (__bf16)v.w };
    *(bf16x4*)(dst + off) = o;
}

// Q,K only: C[t, col] = x[t,:] @ qkv_w[col,:]^T + b  for col in [0, 2048)
__global__ __launch_bounds__(256, 2) void qkv_gemm(
        const __bf16* __restrict__ xbf, const __bf16* __restrict__ wbf,
        const float* __restrict__ bias, __bf16* __restrict__ qk) {
    const int K = E_;
    int wave = threadIdx.x >> 6, lane = threadIdx.x & 63;
    int quad = lane >> 4, lm = lane & 15;
    int rowT = blockIdx.x * 128 + wave * 32;
    int colT = blockIdx.y * 64;
    f32x4 acc[2][4] = {};
    const __bf16* aptr = xbf + (long)(rowT + lm) * K + quad * 8;
    const __bf16* bptr = wbf + (long)(colT + lm) * K + quad * 8;
    for (int k0 = 0; k0 < K; k0 += 32) {
        bf16x8 af[2], bfr[4];
        for (int wm = 0; wm < 2; wm++)
            af[wm] = *(const bf16x8*)(aptr + (long)wm * 16 * K + k0);
        for (int wn = 0; wn < 4; wn++)
            bfr[wn] = *(const bf16x8*)(bptr + (long)wn * 16 * K + k0);
        for (int wm = 0; wm < 2; wm++)
            for (int wn = 0; wn < 4; wn++)
                acc[wm][wn] = mfma16(af[wm], bfr[wn], acc[wm][wn]);
    }
    for (int wn = 0; wn < 4; wn++) {
        int col = colT + wn * 16 + lm;
        float bv = bias[col];
        int which = col >> 10, rem = col & 1023;
        int h = rem >> 6, d = rem & 63;
        for (int wm = 0; wm < 2; wm++) {
            int rowb = rowT + wm * 16 + quad * 4;
            for (int r = 0; r < 4; r++) {
                int row = rowb + r;
                int b = row >> 11, s = row & 2047;
                float v = acc[wm][wn][r] + bv;
                qk[(long)((which * B_ + b) * H_ + h) * (S_ * D_) + (long)s * D_ + d] = (__bf16)v;
            }
        }
    }
}

// VT[(b,h,d), t] = sum_k Wv[h*64+d, k] * x[t, k] + bias_v  -> [B,H,D,S] bf16
__global__ __launch_bounds__(256, 2) void vt_gemm(
        const __bf16* __restrict__ xbf, const __bf16* __restrict__ wvbf,
        const float* __restrict__ bias, __bf16* __restrict__ vt) {
    const int K = E_;
    int wave = threadIdx.x >> 6, lane = threadIdx.x & 63;
    int quad = lane >> 4, lm = lane & 15;
    int rowT = blockIdx.x * 128 + wave * 32;   // M = 1024 (v-row)
    int colT = blockIdx.y * 64;                // N = 4096 (token)
    f32x4 acc[2][4] = {};
    const __bf16* aptr = wvbf + (long)(rowT + lm) * K + quad * 8;
    const __bf16* bptr = xbf + (long)(colT + lm) * K + quad * 8;
    for (int k0 = 0; k0 < K; k0 += 32) {
        bf16x8 af[2], bfr[4];
        for (int wm = 0; wm < 2; wm++)
            af[wm] = *(const bf16x8*)(aptr + (long)wm * 16 * K + k0);
        for (int wn = 0; wn < 4; wn++)
            bfr[wn] = *(const bf16x8*)(bptr + (long)wn * 16 * K + k0);
        for (int wm = 0; wm < 2; wm++)
            for (int wn = 0; wn < 4; wn++)
                acc[wm][wn] = mfma16(af[wm], bfr[wn], acc[wm][wn]);
    }
    for (int wn = 0; wn < 4; wn++) {
        int t = colT + wn * 16 + lm;
        int b = t >> 11, s = t & 2047;
        for (int wm = 0; wm < 2; wm++) {
            int rowb = rowT + wm * 16 + quad * 4;
            for (int r = 0; r < 4; r++) {
                int m = rowb + r;          // v-row: h*64+d
                int h = m >> 6, d = m & 63;
                float v = acc[wm][wn][r] + bias[2048 + m];
                vt[(long)((b * H_ + h) * D_ + d) * S_ + s] = (__bf16)v;
            }
        }
    }
}

// r4: latency-bound fix. (a) blockIdx.x = bh so all q-tiles of one head share
// an XCD (K/V stay in that XCD's L2: 4 heads x 512 KB = 2 MB of 4 MB).
// (b) software-pipelined register prefetch: K/mask for kb+64 issued right
// after current QK MFMAs, V for kb+64 right after current PV MFMAs -> each
// load hides behind ~a full iteration (~700 cyc) of independent work.
__global__ __launch_bounds__(256, 2) void flash_attn(
        const __bf16* __restrict__ qk, const __bf16* __restrict__ vt,
        const int* __restrict__ mask, __bf16* __restrict__ attn) {
    int wave = threadIdx.x >> 6, lane = threadIdx.x & 63;
    int quad = lane >> 4, lm = lane & 15;
    int bh = blockIdx.x;      // 0..31  (XCD = bh % 8 under round-robin)
    int qtile = blockIdx.y;   // 0..31
    int b = bh >> 4, h = bh & 15;
    const long BHSD = (long)B_ * H_ * S_ * D_;
    const __bf16* qp  = qk + (long)bh * (S_ * D_);
    const __bf16* kp  = qk + BHSD + (long)bh * (S_ * D_);
    const __bf16* vtp = vt + (long)bh * (D_ * S_);   // [d][s]
    const int* mrow = mask + b * S_;

    int q0 = qtile * 64 + wave * 16;
    bf16x8 qa[2];
    for (int t = 0; t < 2; t++)
        qa[t] = *(const bf16x8*)(qp + (long)(q0 + lm) * D_ + t * 32 + quad * 8);

    f32x4 O[4] = {};
    float m_run[4], l_run[4];
    for (int r = 0; r < 4; r++) { m_run[r] = -1e30f; l_run[r] = 0.f; }

    __shared__ __bf16 Plds[4][16][72];   // wave-private; stride 72 to spread banks

    // ---- prologue: load tile kb=0 ----
    bf16x8 kf[4][2], vf[4][2];
    int mk[4];
    for (int hh = 0; hh < 4; hh++) {
        const __bf16* krow = kp + (long)(hh * 16 + lm) * D_ + quad * 8;
        kf[hh][0] = *(const bf16x8*)(krow);
        kf[hh][1] = *(const bf16x8*)(krow + 32);
        mk[hh] = mrow[hh * 16 + lm];
    }
    for (int c = 0; c < 4; c++) {
        const __bf16* vrow = vtp + (long)(c * 16 + lm) * S_ + quad * 8;
        vf[c][0] = *(const bf16x8*)(vrow);
        vf[c][1] = *(const bf16x8*)(vrow + 32);
    }

    for (int kb = 0; kb < S_; kb += 64) {
        int nkb = (kb + 64 < S_) ? kb + 64 : 0;   // redundant reload of tile 0 on last iter

        // ---- QK^T with current K ----
        f32x4 sf[4];
        for (int hh = 0; hh < 4; hh++) {
            f32x4 z = {};
            z = mfma16(qa[0], kf[hh][0], z);
            sf[hh] = mfma16(qa[1], kf[hh][1], z);
        }
        // ---- prefetch next K + mask (hidden behind softmax + PV) ----
        bf16x8 nk[4][2];
        int nmk[4];
        for (int hh = 0; hh < 4; hh++) {
            const __bf16* krow = kp + (long)(nkb + hh * 16 + lm) * D_ + quad * 8;
            nk[hh][0] = *(const bf16x8*)(krow);
            nk[hh][1] = *(const bf16x8*)(krow + 32);
            nmk[hh] = mrow[nkb + hh * 16 + lm];
        }

        // ---- online softmax ----
        float p[4][4], vmax[4];
        for (int r = 0; r < 4; r++) vmax[r] = -1e30f;
        for (int hh = 0; hh < 4; hh++)
            for (int r = 0; r < 4; r++) {
                float s = mk[hh] ? sf[hh][r] * 0.125f : -1e30f;
                p[hh][r] = s;
                vmax[r] = fmaxf(vmax[r], s);
            }
        for (int off = 1; off < 16; off <<= 1)
            for (int r = 0; r < 4; r++)
                vmax[r] = fmaxf(vmax[r], __shfl_xor(vmax[r], off));
        float alpha[4], rs[4];
        for (int r = 0; r < 4; r++) {
            float mn = fmaxf(m_run[r], vmax[r]);
            alpha[r] = __expf(m_run[r] - mn);
            m_run[r] = mn;
            float acc = 0.f;
            for (int hh = 0; hh < 4; hh++) {
                p[hh][r] = __expf(p[hh][r] - mn);
                acc += p[hh][r];
            }
            rs[r] = acc;
        }
        for (int off = 1; off < 16; off <<= 1)
            for (int r = 0; r < 4; r++)
                rs[r] += __shfl_xor(rs[r], off);
        for (int r = 0; r < 4; r++) l_run[r] = l_run[r] * alpha[r] + rs[r];
        for (int c = 0; c < 4; c++)
            for (int r = 0; r < 4; r++)
                O[c][r] *= alpha[r];
        // P: C-layout -> LDS -> A-layout (wave-private slice, no barrier needed)
        for (int hh = 0; hh < 4; hh++)
            for (int r = 0; r < 4; r++)
                Plds[wave][quad * 4 + r][hh * 16 + lm] = (__bf16)p[hh][r];
        bf16x8 pa0 = *(const bf16x8*)(&Plds[wave][lm][quad * 8]);
        bf16x8 pa1 = *(const bf16x8*)(&Plds[wave][lm][32 + quad * 8]);

        // ---- PV with current V ----
        for (int c = 0; c < 4; c++) {
            O[c] = mfma16(pa0, vf[c][0], O[c]);
            O[c] = mfma16(pa1, vf[c][1], O[c]);
        }
        // ---- prefetch next V (hidden behind next iter's QK + softmax) ----
        bf16x8 nv[4][2];
        for (int c = 0; c < 4; c++) {
            const __bf16* vrow = vtp + (long)(c * 16 + lm) * S_ + nkb + quad * 8;
            nv[c][0] = *(const bf16x8*)(vrow);
            nv[c][1] = *(const bf16x8*)(vrow + 32);
        }
        for (int hh = 0; hh < 4; hh++) {
            kf[hh][0] = nk[hh][0]; kf[hh][1] = nk[hh][1];
            mk[hh] = nmk[hh];
        }
        for (int c = 0; c < 4; c++) {
            vf[c][0] = nv[c][0]; vf[c][1] = nv[c][1];
        }
    }
    float inv[4];
    for (int r = 0; r < 4; r++) inv[r] = (l_run[r] > 0.f) ? 1.f / l_run[r] : 0.f;
    for (int c = 0; c < 4; c++)
        for (int r = 0; r < 4; r++) {
            int s = q0 + quad * 4 + r;
            int e = h * 64 + c * 16 + lm;
            attn[(long)(b * S_ + s) * E_ + e] = (__bf16)(O[c][r] * inv[r]);
        }
}

// out[M,N] = A[M,K] @ W[N,K]^T + bias, fp32 out
__global__ __launch_bounds__(256, 2) void proj_gemm(
        const __bf16* __restrict__ abf, const __bf16* __restrict__ wbf,
        const float* __restrict__ bias, float* __restrict__ out) {
    const int K = E_;
    int wave = threadIdx.x >> 6, lane = threadIdx.x & 63;
    int quad = lane >> 4, lm = lane & 15;
    int rowT = blockIdx.x * 128 + wave * 32;
    int colT = blockIdx.y * 64;
    f32x4 acc[2][4] = {};
    const __bf16* aptr = abf + (long)(rowT + lm) * K + quad * 8;
    const __bf16* bptr = wbf + (long)(colT + lm) * K + quad * 8;
    for (int k0 = 0; k0 < K; k0 += 32) {
        bf16x8 af[2], bfr[4];
        for (int wm = 0; wm < 2; wm++)
            af[wm] = *(const bf16x8*)(aptr + (long)wm * 16 * K + k0);
        for (int wn = 0; wn < 4; wn++)
            bfr[wn] = *(const bf16x8*)(bptr + (long)wn * 16 * K + k0);
        for (int wm = 0; wm < 2; wm++)
            for (int wn = 0; wn < 4; wn++)
                acc[wm][wn] = mfma16(af[wm], bfr[wn], acc[wm][wn]);
    }
    for (int wn = 0; wn < 4; wn++) {
        int col = colT + wn * 16 + lm;
        float bv = bias[col];
        for (int wm = 0; wm < 2; wm++) {
            int rowb = rowT + wm * 16 + quad * 4;
            for (int r = 0; r < 4; r++) {
                int row = rowb + r;
                out[(long)row * E_ + col] = acc[wm][wn][r] + bv;
            }
        }
    }
}

extern "C" void kernel_launch(void* const* d_in, const int* in_sizes, int n_in,
                              void* d_out, int out_size, void* d_ws, size_t ws_size,
                              hipStream_t stream) {
    const float* x      = (const float*)d_in[0];
    const int*   mask   = (const int*)d_in[1];
    const float* qkv_w  = (const float*)d_in[2];
    const float* qkv_b  = (const float*)d_in[3];
    const float* proj_w = (const float*)d_in[4];
    const float* proj_b = (const float*)d_in[5];
    float* out = (float*)d_out;
    __bf16* ws = (__bf16*)d_ws;

    __bf16* x_bf     = ws;
    __bf16* qkvw_bf  = ws + 4194304;
    __bf16* projw_bf = ws + 7340032;
    __bf16* qk_bf    = ws + 8388608;
    __bf16* vt_bf    = ws + 16777216;
    __bf16* attn_bf  = ws + 20971520;

    convert_kernel<<<8192, 256, 0, stream>>>(x, qkv_w, proj_w, ws);
    qkv_gemm<<<dim3(32, 32), 256, 0, stream>>>(x_bf, qkvw_bf, qkv_b, qk_bf);
    vt_gemm<<<dim3(8, 64), 256, 0, stream>>>(x_bf, qkvw_bf + 2 * E_ * E_, qkv_b, vt_bf);
    // grid: x = bh (XCD affinity), y = qtile
    flash_attn<<<dim3(32, 32), 256, 0, stream>>>(qk_bf, vt_bf, mask, attn_bf);
    proj_gemm<<<dim3(32, 16), 256, 0, stream>>>(attn_bf, projw_bf, proj_b, out);
}

// Round 5
// 395.772 us; speedup vs baseline: 1.2635x; 1.2635x over previous
//
#include <hip/hip_runtime.h>
#include <hip/hip_bf16.h>

#define B_ 2
#define S_ 2048
#define E_ 1024
#define H_ 16
#define D_ 64

typedef __bf16 bf16x8 __attribute__((ext_vector_type(8)));
typedef __bf16 bf16x4 __attribute__((ext_vector_type(4)));
typedef float f32x4 __attribute__((ext_vector_type(4)));

// ws layout in bf16 elements:
//   x_bf     : [4096, 1024]        offset 0         (4194304)
//   qkvw_bf  : [3072, 1024]        offset 4194304   (3145728)
//   projw_bf : [1024, 1024]        offset 7340032   (1048576)
//   qk_bf    : [2][B,H,S,D]        offset 8388608   (8388608)
//   vt_bf    : [B,H,D,S]           offset 16777216  (4194304)
//   attn_bf  : [4096, 1024]        offset 20971520  (4194304)
// total 25165824 elem = 48 MiB

__device__ __forceinline__ f32x4 mfma16(bf16x8 a, bf16x8 b, f32x4 c) {
    return __builtin_amdgcn_mfma_f32_16x16x32_bf16(a, b, c, 0, 0, 0);
}

__global__ __launch_bounds__(256) void convert_kernel(
        const float* __restrict__ x, const float* __restrict__ qkvw,
        const float* __restrict__ projw, __bf16* __restrict__ ws) {
    const long NX = 4194304, NW = 3145728;
    long i = (long)(blockIdx.x * 256 + threadIdx.x) * 4;
    const float* src; __bf16* dst; long off;
    if (i < NX)           { src = x;     dst = ws;           off = i; }
    else if (i < NX + NW) { src = qkvw;  dst = ws + NX;      off = i - NX; }
    else                  { src = projw; dst = ws + NX + NW; off = i - NX - NW; }
    float4 v = *(const float4*)(src + off);
    bf16x4 o = { (__bf16)v.x, (__bf16)v.y, (__bf16)v.z, (__bf16)v.w };
    *(bf16x4*)(dst + off) = o;
}

// Q,K only: C[t, col] = x[t,:] @ qkv_w[col,:]^T + b  for col in [0, 2048)
__global__ __launch_bounds__(256, 2) void qkv_gemm(
        const __bf16* __restrict__ xbf, const __bf16* __restrict__ wbf,
        const float* __restrict__ bias, __bf16* __restrict__ qk) {
    const int K = E_;
    int wave = threadIdx.x >> 6, lane = threadIdx.x & 63;
    int quad = lane >> 4, lm = lane & 15;
    int rowT = blockIdx.x * 128 + wave * 32;
    int colT = blockIdx.y * 64;
    f32x4 acc[2][4] = {};
    const __bf16* aptr = xbf + (long)(rowT + lm) * K + quad * 8;
    const __bf16* bptr = wbf + (long)(colT + lm) * K + quad * 8;
    for (int k0 = 0; k0 < K; k0 += 32) {
        bf16x8 af[2], bfr[4];
        for (int wm = 0; wm < 2; wm++)
            af[wm] = *(const bf16x8*)(aptr + (long)wm * 16 * K + k0);
        for (int wn = 0; wn < 4; wn++)
            bfr[wn] = *(const bf16x8*)(bptr + (long)wn * 16 * K + k0);
        for (int wm = 0; wm < 2; wm++)
            for (int wn = 0; wn < 4; wn++)
                acc[wm][wn] = mfma16(af[wm], bfr[wn], acc[wm][wn]);
    }
    for (int wn = 0; wn < 4; wn++) {
        int col = colT + wn * 16 + lm;
        float bv = bias[col];
        int which = col >> 10, rem = col & 1023;
        int h = rem >> 6, d = rem & 63;
        for (int wm = 0; wm < 2; wm++) {
            int rowb = rowT + wm * 16 + quad * 4;
            for (int r = 0; r < 4; r++) {
                int row = rowb + r;
                int b = row >> 11, s = row & 2047;
                float v = acc[wm][wn][r] + bv;
                qk[(long)((which * B_ + b) * H_ + h) * (S_ * D_) + (long)s * D_ + d] = (__bf16)v;
            }
        }
    }
}

// VT[(b,h,d), t] = sum_k Wv[h*64+d, k] * x[t, k] + bias_v  -> [B,H,D,S] bf16
__global__ __launch_bounds__(256, 2) void vt_gemm(
        const __bf16* __restrict__ xbf, const __bf16* __restrict__ wvbf,
        const float* __restrict__ bias, __bf16* __restrict__ vt) {
    const int K = E_;
    int wave = threadIdx.x >> 6, lane = threadIdx.x & 63;
    int quad = lane >> 4, lm = lane & 15;
    int rowT = blockIdx.x * 128 + wave * 32;   // M = 1024 (v-row)
    int colT = blockIdx.y * 64;                // N = 4096 (token)
    f32x4 acc[2][4] = {};
    const __bf16* aptr = wvbf + (long)(rowT + lm) * K + quad * 8;
    const __bf16* bptr = xbf + (long)(colT + lm) * K + quad * 8;
    for (int k0 = 0; k0 < K; k0 += 32) {
        bf16x8 af[2], bfr[4];
        for (int wm = 0; wm < 2; wm++)
            af[wm] = *(const bf16x8*)(aptr + (long)wm * 16 * K + k0);
        for (int wn = 0; wn < 4; wn++)
            bfr[wn] = *(const bf16x8*)(bptr + (long)wn * 16 * K + k0);
        for (int wm = 0; wm < 2; wm++)
            for (int wn = 0; wn < 4; wn++)
                acc[wm][wn] = mfma16(af[wm], bfr[wn], acc[wm][wn]);
    }
    for (int wn = 0; wn < 4; wn++) {
        int t = colT + wn * 16 + lm;
        int b = t >> 11, s = t & 2047;
        for (int wm = 0; wm < 2; wm++) {
            int rowb = rowT + wm * 16 + quad * 4;
            for (int r = 0; r < 4; r++) {
                int m = rowb + r;          // v-row: h*64+d
                int h = m >> 6, d = m & 63;
                float v = acc[wm][wn][r] + bias[2048 + m];
                vt[(long)((b * H_ + h) * D_ + d) * S_ + s] = (__bf16)v;
            }
        }
    }
}

// r5: dependency-chain restructure.
// - S^T = K*QT (operand swap; A/B frag layouts are the same lane mapping) puts
//   all 16 key-scores of one q-row (q = lane&15) in-lane: softmax reductions
//   become 15 VALU ops + 2 shuffle hops (xor16,32) instead of 8 hops.
// - 2 independent q-tiles per wave: two interleavable chains (in-order issue
//   needs in-wave ILP); K/V/mask loads amortized over 32 q-rows.
// - exp2f in log2 domain: 1 transcendental per score.
// - grid x = bh: all q-tiles of a head on one XCD (r4: FETCH 69.7->12.4 MB).
__global__ __launch_bounds__(256, 2) void flash_attn(
        const __bf16* __restrict__ qk, const __bf16* __restrict__ vt,
        const int* __restrict__ mask, __bf16* __restrict__ attn) {
    int wave = threadIdx.x >> 6, lane = threadIdx.x & 63;
    int quad = lane >> 4, lm = lane & 15;
    int bh = blockIdx.x;      // 0..31  (XCD = bh % 8)
    int qt = blockIdx.y;      // 0..15
    int b = bh >> 4, h = bh & 15;
    const long BHSD = (long)B_ * H_ * S_ * D_;
    const __bf16* qp  = qk + (long)bh * (S_ * D_);
    const __bf16* kp  = qk + BHSD + (long)bh * (S_ * D_);
    const __bf16* vtp = vt + (long)bh * (D_ * S_);   // [d][s]
    const int* mrow = mask + b * S_;

    int q0[2];
    q0[0] = qt * 128 + wave * 16;
    q0[1] = q0[0] + 64;
    bf16x8 qa[2][2];
    for (int t = 0; t < 2; t++)
        for (int x = 0; x < 2; x++)
            qa[t][x] = *(const bf16x8*)(qp + (long)(q0[t] + lm) * D_ + x * 32 + quad * 8);

    f32x4 O[2][4] = {};
    float m2[2], lr[2];
    for (int t = 0; t < 2; t++) { m2[t] = -1e38f; lr[t] = 0.f; }
    const float c1 = 0.1803368801111244f;   // 0.125 * log2(e)

    __shared__ __bf16 Plds[4][2][16][72];   // wave/tile-private, 16B-aligned rows

    for (int kb = 0; kb < S_; kb += 64) {
        // K tile (A-operand role: lane holds K[key=16hh+lm][quad*8+j]) + mask
        bf16x8 kf[4][2];
        int4 mq[4];
        for (int hh = 0; hh < 4; hh++) {
            const __bf16* krow = kp + (long)(kb + hh * 16 + lm) * D_ + quad * 8;
            kf[hh][0] = *(const bf16x8*)(krow);
            kf[hh][1] = *(const bf16x8*)(krow + 32);
            mq[hh] = *(const int4*)(mrow + kb + hh * 16 + quad * 4);
        }
        // V^T tile (B-operand role: lane holds V[kb+quad*8+j][d=c*16+lm])
        bf16x8 vf[4][2];
        for (int c = 0; c < 4; c++) {
            const __bf16* vrow = vtp + (long)(c * 16 + lm) * S_ + kb + quad * 8;
            vf[c][0] = *(const bf16x8*)(vrow);
            vf[c][1] = *(const bf16x8*)(vrow + 32);
        }
        // S^T[key][q]: row = quad*4+r = local key, col = lm = local q
        f32x4 st[2][4];
        for (int hh = 0; hh < 4; hh++)
            for (int t = 0; t < 2; t++) {
                f32x4 z = {};
                z = mfma16(kf[hh][0], qa[t][0], z);
                st[t][hh] = mfma16(kf[hh][1], qa[t][1], z);
            }
        // masked, log2-scaled scores
        float s2[2][4][4];
        for (int hh = 0; hh < 4; hh++) {
            int mr[4] = {mq[hh].x, mq[hh].y, mq[hh].z, mq[hh].w};
            for (int t = 0; t < 2; t++)
                for (int r = 0; r < 4; r++)
                    s2[t][hh][r] = mr[r] ? st[t][hh][r] * c1 : -1e38f;
        }
        // online softmax per tile (chains independent -> scheduler interleaves)
        float p[2][4][4], alpha[2];
        for (int t = 0; t < 2; t++) {
            float mx = s2[t][0][0];
            for (int hh = 0; hh < 4; hh++)
                for (int r = 0; r < 4; r++)
                    mx = fmaxf(mx, s2[t][hh][r]);
            mx = fmaxf(mx, __shfl_xor(mx, 16));
            mx = fmaxf(mx, __shfl_xor(mx, 32));
            float mn = fmaxf(m2[t], mx);
            alpha[t] = exp2f(m2[t] - mn);
            m2[t] = mn;
            float sum = 0.f;
            for (int hh = 0; hh < 4; hh++)
                for (int r = 0; r < 4; r++) {
                    float e = exp2f(s2[t][hh][r] - mn);
                    e = (s2[t][hh][r] <= -1e37f) ? 0.f : e;   // all-masked guard
                    p[t][hh][r] = e;
                    sum += e;
                }
            sum += __shfl_xor(sum, 16);
            sum += __shfl_xor(sum, 32);
            lr[t] = lr[t] * alpha[t] + sum;
        }
        for (int t = 0; t < 2; t++) {
            // rescale O rows (row = q = quad*4+r; alpha lives at lane q)
            for (int r = 0; r < 4; r++) {
                float av = __shfl(alpha[t], quad * 4 + r);
                for (int c = 0; c < 4; c++)
                    O[t][c][r] *= av;
            }
            // P -> LDS in A-layout: row = q = lm, cols = keys (4 packed per write)
            for (int hh = 0; hh < 4; hh++) {
                bf16x4 pk = { (__bf16)p[t][hh][0], (__bf16)p[t][hh][1],
                              (__bf16)p[t][hh][2], (__bf16)p[t][hh][3] };
                *(bf16x4*)(&Plds[wave][t][lm][hh * 16 + quad * 4]) = pk;
            }
            bf16x8 pa0 = *(const bf16x8*)(&Plds[wave][t][lm][quad * 8]);
            bf16x8 pa1 = *(const bf16x8*)(&Plds[wave][t][lm][32 + quad * 8]);
            for (int c = 0; c < 4; c++) {
                O[t][c] = mfma16(pa0, vf[c][0], O[t][c]);
                O[t][c] = mfma16(pa1, vf[c][1], O[t][c]);
            }
        }
    }
    for (int t = 0; t < 2; t++)
        for (int r = 0; r < 4; r++) {
            float lb = __shfl(lr[t], quad * 4 + r);
            float inv = lb > 0.f ? 1.f / lb : 0.f;
            int s = q0[t] + quad * 4 + r;
            for (int c = 0; c < 4; c++) {
                int e = h * 64 + c * 16 + lm;
                attn[(long)(b * S_ + s) * E_ + e] = (__bf16)(O[t][c][r] * inv);
            }
        }
}

// out[M,N] = A[M,K] @ W[N,K]^T + bias, fp32 out
__global__ __launch_bounds__(256, 2) void proj_gemm(
        const __bf16* __restrict__ abf, const __bf16* __restrict__ wbf,
        const float* __restrict__ bias, float* __restrict__ out) {
    const int K = E_;
    int wave = threadIdx.x >> 6, lane = threadIdx.x & 63;
    int quad = lane >> 4, lm = lane & 15;
    int rowT = blockIdx.x * 128 + wave * 32;
    int colT = blockIdx.y * 64;
    f32x4 acc[2][4] = {};
    const __bf16* aptr = abf + (long)(rowT + lm) * K + quad * 8;
    const __bf16* bptr = wbf + (long)(colT + lm) * K + quad * 8;
    for (int k0 = 0; k0 < K; k0 += 32) {
        bf16x8 af[2], bfr[4];
        for (int wm = 0; wm < 2; wm++)
            af[wm] = *(const bf16x8*)(aptr + (long)wm * 16 * K + k0);
        for (int wn = 0; wn < 4; wn++)
            bfr[wn] = *(const bf16x8*)(bptr + (long)wn * 16 * K + k0);
        for (int wm = 0; wm < 2; wm++)
            for (int wn = 0; wn < 4; wn++)
                acc[wm][wn] = mfma16(af[wm], bfr[wn], acc[wm][wn]);
    }
    for (int wn = 0; wn < 4; wn++) {
        int col = colT + wn * 16 + lm;
        float bv = bias[col];
        for (int wm = 0; wm < 2; wm++) {
            int rowb = rowT + wm * 16 + quad * 4;
            for (int r = 0; r < 4; r++) {
                int row = rowb + r;
                out[(long)row * E_ + col] = acc[wm][wn][r] + bv;
            }
        }
    }
}

extern "C" void kernel_launch(void* const* d_in, const int* in_sizes, int n_in,
                              void* d_out, int out_size, void* d_ws, size_t ws_size,
                              hipStream_t stream) {
    const float* x      = (const float*)d_in[0];
    const int*   mask   = (const int*)d_in[1];
    const float* qkv_w  = (const float*)d_in[2];
    const float* qkv_b  = (const float*)d_in[3];
    const float* proj_w = (const float*)d_in[4];
    const float* proj_b = (const float*)d_in[5];
    float* out = (float*)d_out;
    __bf16* ws = (__bf16*)d_ws;

    __bf16* x_bf     = ws;
    __bf16* qkvw_bf  = ws + 4194304;
    __bf16* projw_bf = ws + 7340032;
    __bf16* qk_bf    = ws + 8388608;
    __bf16* vt_bf    = ws + 16777216;
    __bf16* attn_bf  = ws + 20971520;

    convert_kernel<<<8192, 256, 0, stream>>>(x, qkv_w, proj_w, ws);
    qkv_gemm<<<dim3(32, 32), 256, 0, stream>>>(x_bf, qkvw_bf, qkv_b, qk_bf);
    vt_gemm<<<dim3(8, 64), 256, 0, stream>>>(x_bf, qkvw_bf + 2 * E_ * E_, qkv_b, vt_bf);
    // grid: x = bh (XCD affinity), y = qtile (128 q-rows per block)
    flash_attn<<<dim3(32, 16), 256, 0, stream>>>(qk_bf, vt_bf, mask, attn_bf);
    proj_gemm<<<dim3(32, 16), 256, 0, stream>>>(attn_bf, projw_bf, proj_b, out);
}

// Round 6
// 291.674 us; speedup vs baseline: 1.7145x; 1.3569x over previous
//
#include <hip/hip_runtime.h>
#include <hip/hip_bf16.h>

#define B_ 2
#define S_ 2048
#define E_ 1024
#define H_ 16
#define D_ 64

typedef __bf16 bf16x8 __attribute__((ext_vector_type(8)));
typedef __bf16 bf16x4 __attribute__((ext_vector_type(4)));
typedef float f32x4 __attribute__((ext_vector_type(4)));

// ws layout in bf16 elements:
//   x_bf     : [4096, 1024]        offset 0         (4194304)
//   qkvw_bf  : [3072, 1024]        offset 4194304   (3145728)
//   projw_bf : [1024, 1024]        offset 7340032   (1048576)
//   qk_bf    : [2][B,H,S,D]        offset 8388608   (8388608)
//   vt_bf    : [B,H,D,S]           offset 16777216  (4194304)
//   attn_bf  : [4096, 1024]        offset 20971520  (4194304)
// total 25165824 elem = 48 MiB

__device__ __forceinline__ f32x4 mfma16(bf16x8 a, bf16x8 b, f32x4 c) {
    return __builtin_amdgcn_mfma_f32_16x16x32_bf16(a, b, c, 0, 0, 0);
}

// async global->LDS, 16B per lane; LDS dest = wave-uniform base + lane*16
__device__ __forceinline__ void gl_lds16(const __bf16* g, __bf16* l) {
    __builtin_amdgcn_global_load_lds(
        (const __attribute__((address_space(1))) unsigned int*)g,
        (__attribute__((address_space(3))) unsigned int*)l, 16, 0, 0);
}

__global__ __launch_bounds__(256) void convert_kernel(
        const float* __restrict__ x, const float* __restrict__ qkvw,
        const float* __restrict__ projw, __bf16* __restrict__ ws) {
    const long NX = 4194304, NW = 3145728;
    long i = (long)(blockIdx.x * 256 + threadIdx.x) * 4;
    const float* src; __bf16* dst; long off;
    if (i < NX)           { src = x;     dst = ws;           off = i; }
    else if (i < NX + NW) { src = qkvw;  dst = ws + NX;      off = i - NX; }
    else                  { src = projw; dst = ws + NX + NW; off = i - NX - NW; }
    float4 v = *(const float4*)(src + off);
    bf16x4 o = { (__bf16)v.x, (__bf16)v.y, (__bf16)v.z, (__bf16)v.w };
    *(bf16x4*)(dst + off) = o;
}

// m97-style GEMM core: 128x128 tile/block (4 waves, 64x64 each), BK=64,
// LDS staging via global_load_lds dwordx4, 2-barrier K-loop.
// LDS layout: T[row][k] row-major, row stride 64 elems (128 B); staging slot
// s (16 B) = row s/8, chunk s%8 -> exactly the lane-order contiguity
// global_load_lds requires (no padding allowed).
__device__ __forceinline__ void gemm_core(
        const __bf16* __restrict__ A, const __bf16* __restrict__ Bm,
        int rowT, int colT, int K,
        __bf16* AT, __bf16* BT, f32x4 acc[4][4]) {
    int tid = threadIdx.x;
    int wave = tid >> 6, lane = tid & 63;
    int quad = lane >> 4, lm = lane & 15;
    int wy = wave >> 1, wx = wave & 1;
    int srow = wave * 8 + (lane >> 3);   // + i*32 per staging instr
    int schunk = lane & 7;
    const __bf16* ap = A + (long)(rowT + srow) * K + schunk * 8;
    const __bf16* bp = Bm + (long)(colT + srow) * K + schunk * 8;
    for (int k0 = 0; k0 < K; k0 += 64) {
        __syncthreads();   // previous compute done before LDS overwrite
        for (int i = 0; i < 4; i++) {
            gl_lds16(ap + (long)i * 32 * K + k0, AT + (i * 256 + wave * 64) * 8);
            gl_lds16(bp + (long)i * 32 * K + k0, BT + (i * 256 + wave * 64) * 8);
        }
        __syncthreads();   // compiler emits vmcnt(0) drain here
        for (int ks = 0; ks < 2; ks++) {
            bf16x8 af[4], bfr[4];
            for (int m = 0; m < 4; m++)
                af[m] = *(const bf16x8*)(AT + (wy * 64 + m * 16 + lm) * 64 + ks * 32 + quad * 8);
            for (int n = 0; n < 4; n++)
                bfr[n] = *(const bf16x8*)(BT + (wx * 64 + n * 16 + lm) * 64 + ks * 32 + quad * 8);
            for (int m = 0; m < 4; m++)
                for (int n = 0; n < 4; n++)
                    acc[m][n] = mfma16(af[m], bfr[n], acc[m][n]);
        }
    }
}

// Q,K: C[t, col] = x[t,:] @ qkv_w[col,:]^T + b, col in [0,2048), scatter to qk
__global__ __launch_bounds__(256, 2) void qkv_gemm(
        const __bf16* __restrict__ xbf, const __bf16* __restrict__ wbf,
        const float* __restrict__ bias, __bf16* __restrict__ qk) {
    __shared__ __align__(16) __bf16 AT[128 * 64];
    __shared__ __align__(16) __bf16 BT[128 * 64];
    f32x4 acc[4][4] = {};
    int rowT = blockIdx.x * 128, colT = blockIdx.y * 128;
    gemm_core(xbf, wbf, rowT, colT, E_, AT, BT, acc);
    int wave = threadIdx.x >> 6, lane = threadIdx.x & 63;
    int quad = lane >> 4, lm = lane & 15;
    int wy = wave >> 1, wx = wave & 1;
    for (int n = 0; n < 4; n++) {
        int col = colT + wx * 64 + n * 16 + lm;
        float bv = bias[col];
        int which = col >> 10, rem = col & 1023;
        int h = rem >> 6, d = rem & 63;
        for (int m = 0; m < 4; m++) {
            int rowb = rowT + wy * 64 + m * 16 + quad * 4;
            for (int r = 0; r < 4; r++) {
                int row = rowb + r;
                int b = row >> 11, s = row & 2047;
                float v = acc[m][n][r] + bv;
                qk[(long)((which * B_ + b) * H_ + h) * (S_ * D_) + (long)s * D_ + d] = (__bf16)v;
            }
        }
    }
}

// VT[(b,h,d), t]: A = Wv rows (M=1024), B = x (N=4096 tokens)
__global__ __launch_bounds__(256, 2) void vt_gemm(
        const __bf16* __restrict__ xbf, const __bf16* __restrict__ wvbf,
        const float* __restrict__ bias, __bf16* __restrict__ vt) {
    __shared__ __align__(16) __bf16 AT[128 * 64];
    __shared__ __align__(16) __bf16 BT[128 * 64];
    f32x4 acc[4][4] = {};
    int rowT = blockIdx.x * 128, colT = blockIdx.y * 128;
    gemm_core(wvbf, xbf, rowT, colT, E_, AT, BT, acc);
    int wave = threadIdx.x >> 6, lane = threadIdx.x & 63;
    int quad = lane >> 4, lm = lane & 15;
    int wy = wave >> 1, wx = wave & 1;
    for (int n = 0; n < 4; n++) {
        int t = colT + wx * 64 + n * 16 + lm;
        int b = t >> 11, s = t & 2047;
        for (int m = 0; m < 4; m++) {
            int rowb = rowT + wy * 64 + m * 16 + quad * 4;
            for (int r = 0; r < 4; r++) {
                int mr = rowb + r;          // v-row: h*64+d
                int h = mr >> 6, d = mr & 63;
                float v = acc[m][n][r] + bias[2048 + mr];
                vt[(long)((b * H_ + h) * D_ + d) * S_ + s] = (__bf16)v;
            }
        }
    }
}

// r5: dependency-chain restructure (kept from r5 — 252->143 us).
// - S^T = K*QT: 16 key-scores per q-row in-lane; 2 shuffle hops not 8.
// - 2 independent q-tiles per wave (in-order issue needs in-wave ILP).
// - grid x = bh: all q-tiles of a head on one XCD (FETCH 69.7->12.4 MB).
__global__ __launch_bounds__(256, 2) void flash_attn(
        const __bf16* __restrict__ qk, const __bf16* __restrict__ vt,
        const int* __restrict__ mask, __bf16* __restrict__ attn) {
    int wave = threadIdx.x >> 6, lane = threadIdx.x & 63;
    int quad = lane >> 4, lm = lane & 15;
    int bh = blockIdx.x;      // 0..31  (XCD = bh % 8)
    int qt = blockIdx.y;      // 0..15
    int b = bh >> 4, h = bh & 15;
    const long BHSD = (long)B_ * H_ * S_ * D_;
    const __bf16* qp  = qk + (long)bh * (S_ * D_);
    const __bf16* kp  = qk + BHSD + (long)bh * (S_ * D_);
    const __bf16* vtp = vt + (long)bh * (D_ * S_);   // [d][s]
    const int* mrow = mask + b * S_;

    int q0[2];
    q0[0] = qt * 128 + wave * 16;
    q0[1] = q0[0] + 64;
    bf16x8 qa[2][2];
    for (int t = 0; t < 2; t++)
        for (int x = 0; x < 2; x++)
            qa[t][x] = *(const bf16x8*)(qp + (long)(q0[t] + lm) * D_ + x * 32 + quad * 8);

    f32x4 O[2][4] = {};
    float m2[2], lr[2];
    for (int t = 0; t < 2; t++) { m2[t] = -1e38f; lr[t] = 0.f; }
    const float c1 = 0.1803368801111244f;   // 0.125 * log2(e)

    __shared__ __bf16 Plds[4][2][16][72];

    for (int kb = 0; kb < S_; kb += 64) {
        bf16x8 kf[4][2];
        int4 mq[4];
        for (int hh = 0; hh < 4; hh++) {
            const __bf16* krow = kp + (long)(kb + hh * 16 + lm) * D_ + quad * 8;
            kf[hh][0] = *(const bf16x8*)(krow);
            kf[hh][1] = *(const bf16x8*)(krow + 32);
            mq[hh] = *(const int4*)(mrow + kb + hh * 16 + quad * 4);
        }
        bf16x8 vf[4][2];
        for (int c = 0; c < 4; c++) {
            const __bf16* vrow = vtp + (long)(c * 16 + lm) * S_ + kb + quad * 8;
            vf[c][0] = *(const bf16x8*)(vrow);
            vf[c][1] = *(const bf16x8*)(vrow + 32);
        }
        f32x4 st[2][4];
        for (int hh = 0; hh < 4; hh++)
            for (int t = 0; t < 2; t++) {
                f32x4 z = {};
                z = mfma16(kf[hh][0], qa[t][0], z);
                st[t][hh] = mfma16(kf[hh][1], qa[t][1], z);
            }
        float s2[2][4][4];
        for (int hh = 0; hh < 4; hh++) {
            int mr[4] = {mq[hh].x, mq[hh].y, mq[hh].z, mq[hh].w};
            for (int t = 0; t < 2; t++)
                for (int r = 0; r < 4; r++)
                    s2[t][hh][r] = mr[r] ? st[t][hh][r] * c1 : -1e38f;
        }
        float p[2][4][4], alpha[2];
        for (int t = 0; t < 2; t++) {
            float mx = s2[t][0][0];
            for (int hh = 0; hh < 4; hh++)
                for (int r = 0; r < 4; r++)
                    mx = fmaxf(mx, s2[t][hh][r]);
            mx = fmaxf(mx, __shfl_xor(mx, 16));
            mx = fmaxf(mx, __shfl_xor(mx, 32));
            float mn = fmaxf(m2[t], mx);
            alpha[t] = exp2f(m2[t] - mn);
            m2[t] = mn;
            float sum = 0.f;
            for (int hh = 0; hh < 4; hh++)
                for (int r = 0; r < 4; r++) {
                    float e = exp2f(s2[t][hh][r] - mn);
                    e = (s2[t][hh][r] <= -1e37f) ? 0.f : e;
                    p[t][hh][r] = e;
                    sum += e;
                }
            sum += __shfl_xor(sum, 16);
            sum += __shfl_xor(sum, 32);
            lr[t] = lr[t] * alpha[t] + sum;
        }
        for (int t = 0; t < 2; t++) {
            for (int r = 0; r < 4; r++) {
                float av = __shfl(alpha[t], quad * 4 + r);
                for (int c = 0; c < 4; c++)
                    O[t][c][r] *= av;
            }
            for (int hh = 0; hh < 4; hh++) {
                bf16x4 pk = { (__bf16)p[t][hh][0], (__bf16)p[t][hh][1],
                              (__bf16)p[t][hh][2], (__bf16)p[t][hh][3] };
                *(bf16x4*)(&Plds[wave][t][lm][hh * 16 + quad * 4]) = pk;
            }
            bf16x8 pa0 = *(const bf16x8*)(&Plds[wave][t][lm][quad * 8]);
            bf16x8 pa1 = *(const bf16x8*)(&Plds[wave][t][lm][32 + quad * 8]);
            for (int c = 0; c < 4; c++) {
                O[t][c] = mfma16(pa0, vf[c][0], O[t][c]);
                O[t][c] = mfma16(pa1, vf[c][1], O[t][c]);
            }
        }
    }
    for (int t = 0; t < 2; t++)
        for (int r = 0; r < 4; r++) {
            float lb = __shfl(lr[t], quad * 4 + r);
            float inv = lb > 0.f ? 1.f / lb : 0.f;
            int s = q0[t] + quad * 4 + r;
            for (int c = 0; c < 4; c++) {
                int e = h * 64 + c * 16 + lm;
                attn[(long)(b * S_ + s) * E_ + e] = (__bf16)(O[t][c][r] * inv);
            }
        }
}

// out[M,N] = A[M,K] @ W[N,K]^T + bias, fp32 out
__global__ __launch_bounds__(256, 2) void proj_gemm(
        const __bf16* __restrict__ abf, const __bf16* __restrict__ wbf,
        const float* __restrict__ bias, float* __restrict__ out) {
    __shared__ __align__(16) __bf16 AT[128 * 64];
    __shared__ __align__(16) __bf16 BT[128 * 64];
    f32x4 acc[4][4] = {};
    int rowT = blockIdx.x * 128, colT = blockIdx.y * 128;
    gemm_core(abf, wbf, rowT, colT, E_, AT, BT, acc);
    int wave = threadIdx.x >> 6, lane = threadIdx.x & 63;
    int quad = lane >> 4, lm = lane & 15;
    int wy = wave >> 1, wx = wave & 1;
    for (int n = 0; n < 4; n++) {
        int col = colT + wx * 64 + n * 16 + lm;
        float bv = bias[col];
        for (int m = 0; m < 4; m++) {
            int rowb = rowT + wy * 64 + m * 16 + quad * 4;
            for (int r = 0; r < 4; r++) {
                int row = rowb + r;
                out[(long)row * E_ + col] = acc[m][n][r] + bv;
            }
        }
    }
}

extern "C" void kernel_launch(void* const* d_in, const int* in_sizes, int n_in,
                              void* d_out, int out_size, void* d_ws, size_t ws_size,
                              hipStream_t stream) {
    const float* x      = (const float*)d_in[0];
    const int*   mask   = (const int*)d_in[1];
    const float* qkv_w  = (const float*)d_in[2];
    const float* qkv_b  = (const float*)d_in[3];
    const float* proj_w = (const float*)d_in[4];
    const float* proj_b = (const float*)d_in[5];
    float* out = (float*)d_out;
    __bf16* ws = (__bf16*)d_ws;

    __bf16* x_bf     = ws;
    __bf16* qkvw_bf  = ws + 4194304;
    __bf16* projw_bf = ws + 7340032;
    __bf16* qk_bf    = ws + 8388608;
    __bf16* vt_bf    = ws + 16777216;
    __bf16* attn_bf  = ws + 20971520;

    convert_kernel<<<8192, 256, 0, stream>>>(x, qkv_w, proj_w, ws);
    qkv_gemm<<<dim3(32, 16), 256, 0, stream>>>(x_bf, qkvw_bf, qkv_b, qk_bf);
    vt_gemm<<<dim3(8, 32), 256, 0, stream>>>(x_bf, qkvw_bf + 2 * E_ * E_, qkv_b, vt_bf);
    // grid: x = bh (XCD affinity), y = qtile (128 q-rows per block)
    flash_attn<<<dim3(32, 16), 256, 0, stream>>>(qk_bf, vt_bf, mask, attn_bf);
    proj_gemm<<<dim3(32, 8), 256, 0, stream>>>(attn_bf, projw_bf, proj_b, out);
}